// Round 7
// baseline (221.646 us; speedup 1.0000x reference)
//
#include <hip/hip_runtime.h>
#include <hip/hip_bf16.h>

typedef __attribute__((ext_vector_type(8))) short short8;
typedef __attribute__((ext_vector_type(16))) float f32x16;
typedef __attribute__((ext_vector_type(4))) unsigned uint4v;
typedef unsigned int u32;

#define D_DIM 128
#define G_DIM 9
#define O_DIM 128
#define K_DIM 1152
#define BROWS 256
#define NTHR 512
#define INV2PI 0.15915494309189535f

__device__ __forceinline__ short f2bf(float f) {
  unsigned u = __float_as_uint(f);
  unsigned r = (u + 0x7FFFu + ((u >> 16) & 1u)) >> 16;
  return (short)r;
}

__device__ __forceinline__ unsigned pk2bf(float a, float b) {
  __hip_bfloat162 h = __float22bfloat162_rn(float2{a, b});   // v_cvt_pk_bf16_f32, a->low
  return *reinterpret_cast<unsigned*>(&h);
}

// Prep:
//  Bp (ws): K-major: [g][kk][hi][o][j]  (g*16384 + kk*2048 + hi*1024 + o*8 + j shorts)
//           value = bf16(amp[o][d]/..), d = kk*16 + hi*8 + j
//           -> quarter-wave b128 reads are 256B contiguous: conflict-free
//  pt2 (ws): [g][d] = phase[d][g] / 2pi
//  fq2 (ws): freq[g] / 2pi
__global__ void sinekan_prep(const float* __restrict__ amp,
                             const float* __restrict__ phase,
                             const float* __restrict__ freq,
                             short* __restrict__ Bp,
                             float* __restrict__ pt2,
                             float* __restrict__ fq2) {
  int i = blockIdx.x * blockDim.x + threadIdx.x;
  if (i < G_DIM * O_DIM * D_DIM) {
    int g    = i >> 14;
    int rem  = i & 16383;
    int kk   = rem >> 11;
    int rem2 = rem & 2047;
    int hi   = rem2 >> 10;
    int rem3 = rem2 & 1023;
    int o    = rem3 >> 3;
    int j    = rem3 & 7;
    int d    = kk * 16 + hi * 8 + j;
    Bp[i] = f2bf(amp[(o * D_DIM + d) * G_DIM + g]);
  }
  if (i < K_DIM) {
    int g = i >> 7, d = i & 127;
    pt2[i] = phase[d * G_DIM + g] * INV2PI;
  }
  if (i < G_DIM) fq2[i] = freq[i] * INV2PI;
}

__device__ __forceinline__ void stage_b(const short* __restrict__ Bp, short* dst_lds,
                                        int g, int tid) {
  // pure linear copy (LDS offset == global offset within the 32KB chunk)
  const char* src = (const char*)Bp + ((size_t)g << 15) + tid * 16;
  char* dst = (char*)dst_lds + (tid >> 6) * 1024;
#pragma unroll
  for (int c = 0; c < 4; ++c) {
    __builtin_amdgcn_global_load_lds(
        (const __attribute__((address_space(1))) u32*)(src + c * 8192),
        (__attribute__((address_space(3))) u32*)(dst + c * 8192), 16, 0, 0);
  }
}

__global__ __launch_bounds__(NTHR, 3)
void sinekan_fused(const float* __restrict__ x,
                   const int* __restrict__ mask,
                   const float* __restrict__ bias,
                   const float* __restrict__ lnw,
                   const float* __restrict__ lnb,
                   const short* __restrict__ Bp,
                   const float* __restrict__ pt2,
                   const float* __restrict__ fq2,
                   float* __restrict__ out) {
  __shared__ short b_lds[2][O_DIM * D_DIM];   // 2 x 32 KB, K-major chunks
  __shared__ float pt_lds[G_DIM * D_DIM];     // 4.6 KB
  __shared__ float mu_s[BROWS], rs_s[BROWS], mk_s[BROWS];
  __shared__ float w_s[D_DIM], bb_s[D_DIM];

  const int tid = threadIdx.x;
  const int row0 = blockIdx.x * BROWS;
  const int wv = tid >> 6, lane = tid & 63, lr = lane & 31, hi = lane >> 5;

  // issue B chunk 0 immediately — overlaps with init/stats
  stage_b(Bp, b_lds[0], 0, tid);

  if (tid < D_DIM) { w_s[tid] = lnw[tid]; bb_s[tid] = lnb[tid]; }
  if (tid < BROWS) mk_s[tid] = mask[row0 + tid] ? 1.0f : 0.0f;
  for (int i = tid; i < G_DIM * D_DIM; i += NTHR) pt_lds[i] = pt2[i];

  // ---- LN stats: 16 lanes per row, coalesced; 8 iters x 32 rows ----
  {
    int rloc = tid >> 4, ch = tid & 15;
#pragma unroll 1
    for (int it = 0; it < 8; ++it) {
      int r = it * 32 + rloc;
      const float4* xp = (const float4*)(x + (size_t)(row0 + r) * D_DIM + ch * 8);
      float4 a = xp[0], b = xp[1];
      float s  = a.x + a.y + a.z + a.w + b.x + b.y + b.z + b.w;
      float sq = a.x*a.x + a.y*a.y + a.z*a.z + a.w*a.w
               + b.x*b.x + b.y*b.y + b.z*b.z + b.w*b.w;
#pragma unroll
      for (int off = 1; off < 16; off <<= 1) {
        s  += __shfl_xor(s, off, 64);
        sq += __shfl_xor(sq, off, 64);
      }
      if (ch == 0) {
        float m = s * (1.0f / 128.0f);
        mu_s[r] = m;
        rs_s[r] = rsqrtf(sq * (1.0f / 128.0f) - m * m + 1e-5f);
      }
    }
  }
  __syncthreads();   // stats ready; also drains stage(0) -> b_lds[0] valid

  // ---- cache xn (LN output incl. weight/bias) in f32: 64 VGPR ----
  // wave owns rows wv*32..wv*32+31; lane covers row (wv*32+lr), d-half hi
  float xc[8][8];
  {
    const int rl = wv * 32 + lr;
    const float mu = mu_s[rl], rs = rs_s[rl];
    const float* xr = x + (size_t)(row0 + rl) * D_DIM;
#pragma unroll
    for (int kk = 0; kk < 8; ++kk) {
      const int d0 = kk * 16 + hi * 8;
      float4 xa = *(const float4*)(xr + d0);
      float4 xb = *(const float4*)(xr + d0 + 4);
      float xv[8] = {xa.x, xa.y, xa.z, xa.w, xb.x, xb.y, xb.z, xb.w};
#pragma unroll
      for (int j = 0; j < 8; ++j)
        xc[kk][j] = (xv[j] - mu) * rs * w_s[d0 + j] + bb_s[d0 + j];
    }
  }

  // per-lane hoisted addressing (K-major: + (g&1)*32KB + kk*4KB, frags at +n*512B)
  const char* bbase = (const char*)&b_lds[0][0] + (hi << 11) + (lr << 4);
  const float* ptl = pt_lds + (hi << 3);

  f32x16 acc[4] = {};

#pragma unroll 1
  for (int g = 0; g < G_DIM; ++g) {
    if (g + 1 < G_DIM) stage_b(Bp, b_lds[(g + 1) & 1], g + 1, tid);  // flies under kk-loop
    const float fgv = fq2[g];
    const char* bl = bbase + ((g & 1) << 15);
    const float* ptg = ptl + (g << 7);

    // software pipeline: bf[cur] consumed by MFMA, bf[nxt] loaded for kk+1
    short8 bf[2][4];
    float4 p0 = *(const float4*)(ptg);
    float4 p1 = *(const float4*)(ptg + 4);
    {
      const char* ba = bl;                      // kk = 0
      bf[0][0] = *(const short8*)(ba);
      bf[0][1] = *(const short8*)(ba + 512);
      bf[0][2] = *(const short8*)(ba + 1024);
      bf[0][3] = *(const short8*)(ba + 1536);
    }

#pragma unroll
    for (int kk = 0; kk < 8; ++kk) {
      const int cur = kk & 1, nxt = cur ^ 1;
      float4 q0 = p0, q1 = p1;
      if (kk < 7) {
        const char* bn = bl + ((kk + 1) << 12);
        bf[nxt][0] = *(const short8*)(bn);
        bf[nxt][1] = *(const short8*)(bn + 512);
        bf[nxt][2] = *(const short8*)(bn + 1024);
        bf[nxt][3] = *(const short8*)(bn + 1536);
        q0 = *(const float4*)(ptg + (kk + 1) * 16);
        q1 = *(const float4*)(ptg + (kk + 1) * 16 + 4);
      }

      // A-fragment: fma + v_sin + cvt_pk (pure VALU; covers the LDS latency above)
      const float ph[8] = {p0.x, p0.y, p0.z, p0.w, p1.x, p1.y, p1.z, p1.w};
      uint4v pk;
#pragma unroll
      for (int jj = 0; jj < 4; ++jj) {
        float s0 = __builtin_amdgcn_sinf(fmaf(xc[kk][2*jj],     fgv, ph[2*jj]));
        float s1 = __builtin_amdgcn_sinf(fmaf(xc[kk][2*jj + 1], fgv, ph[2*jj + 1]));
        pk[jj] = pk2bf(s0, s1);
      }
      short8 af = __builtin_bit_cast(short8, pk);

      __builtin_amdgcn_s_setprio(1);
      acc[0] = __builtin_amdgcn_mfma_f32_32x32x16_bf16(af, bf[cur][0], acc[0], 0, 0, 0);
      acc[1] = __builtin_amdgcn_mfma_f32_32x32x16_bf16(af, bf[cur][1], acc[1], 0, 0, 0);
      acc[2] = __builtin_amdgcn_mfma_f32_32x32x16_bf16(af, bf[cur][2], acc[2], 0, 0, 0);
      acc[3] = __builtin_amdgcn_mfma_f32_32x32x16_bf16(af, bf[cur][3], acc[3], 0, 0, 0);
      __builtin_amdgcn_s_setprio(0);

      p0 = q0; p1 = q1;
    }
    __syncthreads();  // drains stage(g+1); b_lds[g&1] free for g+2
  }

  // ---- epilogue: + bias, * mask ----
#pragma unroll
  for (int n = 0; n < 4; ++n) {
    int col = n * 32 + lr;
    float bv = bias[col];
#pragma unroll
    for (int reg = 0; reg < 16; ++reg) {
      int rit  = (reg & 3) + 8 * (reg >> 2) + 4 * hi;
      int rloc = wv * 32 + rit;
      out[(size_t)(row0 + rloc) * O_DIM + col] = (acc[n][reg] + bv) * mk_s[rloc];
    }
  }
}

extern "C" void kernel_launch(void* const* d_in, const int* in_sizes, int n_in,
                              void* d_out, int out_size, void* d_ws, size_t ws_size,
                              hipStream_t stream) {
  const float* x    = (const float*)d_in[0];
  const int* mk     = (const int*)d_in[1];
  const float* freq = (const float*)d_in[2];
  const float* phase= (const float*)d_in[3];
  const float* amp  = (const float*)d_in[4];
  const float* bias = (const float*)d_in[5];
  const float* lnw  = (const float*)d_in[6];
  const float* lnb  = (const float*)d_in[7];
  float* out = (float*)d_out;

  int N = in_sizes[0] / D_DIM;                 // 131072 rows
  short* Bp = (short*)d_ws;                    // 294912 B K-major bf16
  float* pt2 = (float*)((char*)d_ws + (size_t)G_DIM * O_DIM * D_DIM * sizeof(short));
  float* fq2 = pt2 + G_DIM * D_DIM;

  int total = G_DIM * O_DIM * D_DIM;           // 147456
  sinekan_prep<<<(total + 255) / 256, 256, 0, stream>>>(amp, phase, freq, Bp, pt2, fq2);
  sinekan_fused<<<N / BROWS, NTHR, 0, stream>>>(x, mk, bias, lnw, lnb, Bp, pt2, fq2, out);
}